// Round 2
// 271.311 us; speedup vs baseline: 1.0051x; 1.0051x over previous
//
#include <hip/hip_runtime.h>

// One thread per batch row. Row-major x[B][12]; 3x float4 loads per row.
// Circuit algebra: U = Rot4·Rot3·Rot2·Rot1 with Rot = RZ(omega)RY(theta)RZ(phi).
// Adjacent RZ(phi_{g+1})·RZ(omega_g) fuse into RZ(alpha_g); RZ(phi_1) on |0> is a
// global phase (s1=0) and the trailing RZ(omega_4) only phases s0, which |s0|^2
// ignores. Exact reduced circuit:
//   |psi> ~ RY(t4) RZ(a3) RY(t3) RZ(a2) RY(t2) RZ(a1) RY(t1) |0>
// => 7 sin/cos pairs instead of 12, all via native v_sin_f32/v_cos_f32
// (half-angles are O(few radians) -- well inside native range).
__global__ __launch_bounds__(256) void QGN_30219389895238_kernel(
    const float* __restrict__ x,   // [n, 12]
    const float* __restrict__ w,   // [24]
    float* __restrict__ out,       // [n]
    int n) {
  int i = blockIdx.x * blockDim.x + threadIdx.x;
  if (i >= n) return;

  const float4* __restrict__ xr = reinterpret_cast<const float4*>(x + (size_t)i * 12);
  float4 r0 = xr[0];
  float4 r1 = xr[1];
  float4 r2 = xr[2];
  // xv[k]: r0={0,1,2,3} r1={4,5,6,7} r2={8,9,10,11}
  // theta_g = w[6g+2] + xv[3g+1]*w[6g+3]      (g=0..3)
  // alpha_g = (w[6g+4]+xv[3g+2]*w[6g+5]) + (w[6g+6]+xv[3g+3]*w[6g+7])  (g=0..2)
  float ht1 = 0.5f * (w[2]  + r0.y * w[3]);
  float ht2 = 0.5f * (w[8]  + r1.x * w[9]);
  float ht3 = 0.5f * (w[14] + r1.w * w[15]);
  float ht4 = 0.5f * (w[20] + r2.z * w[21]);
  float ha1 = 0.5f * ((w[4]  + r0.z * w[5])  + (w[6]  + r0.w * w[7]));
  float ha2 = 0.5f * ((w[10] + r1.y * w[11]) + (w[12] + r1.z * w[13]));
  float ha3 = 0.5f * ((w[16] + r2.x * w[17]) + (w[18] + r2.y * w[19]));

  // RY(t1) on |0>: state is real (c1, s1).
  float c1 = __cosf(ht1), n1 = __sinf(ht1);

  // RZ(a1): s0 *= e^{-i a1}, s1 *= e^{+i a1} (half-angle already folded).
  float ca = __cosf(ha1), sa = __sinf(ha1);
  float s0r = c1 * ca, s0i = -c1 * sa;
  float s1r = n1 * ca, s1i =  n1 * sa;

  // RY(t2)
  float c = __cosf(ht2), s = __sinf(ht2);
  float t0r = c * s0r - s * s1r, t0i = c * s0i - s * s1i;
  float t1r = s * s0r + c * s1r, t1i = s * s0i + c * s1i;
  s0r = t0r; s0i = t0i; s1r = t1r; s1i = t1i;

  // RZ(a2)
  ca = __cosf(ha2); sa = __sinf(ha2);
  t0r = s0r * ca + s0i * sa; t0i = s0i * ca - s0r * sa;
  t1r = s1r * ca - s1i * sa; t1i = s1i * ca + s1r * sa;
  s0r = t0r; s0i = t0i; s1r = t1r; s1i = t1i;

  // RY(t3)
  c = __cosf(ht3); s = __sinf(ht3);
  t0r = c * s0r - s * s1r; t0i = c * s0i - s * s1i;
  t1r = s * s0r + c * s1r; t1i = s * s0i + c * s1i;
  s0r = t0r; s0i = t0i; s1r = t1r; s1i = t1i;

  // RZ(a3)
  ca = __cosf(ha3); sa = __sinf(ha3);
  t0r = s0r * ca + s0i * sa; t0i = s0i * ca - s0r * sa;
  t1r = s1r * ca - s1i * sa; t1i = s1i * ca + s1r * sa;
  s0r = t0r; s0i = t0i; s1r = t1r; s1i = t1i;

  // RY(t4) -- only s0 needed afterwards.
  c = __cosf(ht4); s = __sinf(ht4);
  t0r = c * s0r - s * s1r; t0i = c * s0i - s * s1i;

  out[i] = t0r * t0r + t0i * t0i;
}

extern "C" void kernel_launch(void* const* d_in, const int* in_sizes, int n_in,
                              void* d_out, int out_size, void* d_ws, size_t ws_size,
                              hipStream_t stream) {
  const float* x = (const float*)d_in[0];  // [B,12] fp32
  const float* w = (const float*)d_in[1];  // [24]   fp32
  float* out = (float*)d_out;              // [B]    fp32
  int n = in_sizes[0] / 12;
  int block = 256;
  int grid = (n + block - 1) / block;
  QGN_30219389895238_kernel<<<grid, block, 0, stream>>>(x, w, out, n);
}